// Round 2
// baseline (446.668 us; speedup 1.0000x reference)
//
#include <hip/hip_runtime.h>
#include <cstdint>
#include <cstddef>

#define Bv 8
#define Av 16384
#define Sv 2048
#define Dv 512
#define OUTv 512
#define Mv (Bv * Sv)

using u16 = unsigned short;
using f32x4 = __attribute__((ext_vector_type(4))) float;
using bf16x8 = __attribute__((ext_vector_type(8))) short;

__device__ __forceinline__ u16 f2bf(float x) {
  union { float f; uint32_t u; } v; v.f = x;
  uint32_t u = v.u;
  uint32_t r = u + 0x7FFFu + ((u >> 16) & 1u);   // round-to-nearest-even
  return (u16)(r >> 16);
}
__device__ __forceinline__ float bf2f(u16 h) {
  union { uint32_t u; float f; } v; v.u = ((uint32_t)h) << 16; return v.f;
}

// async 16B global->LDS (m97 ladder step-3; compiler never auto-emits this)
__device__ __forceinline__ void gl_lds16(const void* g, void* s) {
  __builtin_amdgcn_global_load_lds(
      (const __attribute__((address_space(1))) unsigned int*)g,
      (__attribute__((address_space(3))) unsigned int*)s, 16, 0, 0);
}

// ---------------------------------------------------------------------------
// Kernel 1: segment-mean pooling. Atoms sorted by residue id per batch, so
// block (b,s) binary-searches its contiguous atom range — no atomics.
// 128 threads, 4 cols each. Atom loop 2-way unrolled (2 loads in flight).
// ---------------------------------------------------------------------------
__global__ __launch_bounds__(128)
void pool_kernel(const float* __restrict__ rep, const int* __restrict__ res_ids,
                 const int* __restrict__ aa_len, u16* __restrict__ pooled,
                 int* __restrict__ counts) {
  const int bs = blockIdx.x;
  const int b = bs >> 11;          // /Sv
  const int s = bs & (Sv - 1);
  int alen = aa_len[b];
  alen = alen < 0 ? 0 : (alen > Av ? Av : alen);
  const int* ids = res_ids + b * Av;
  int lo = 0, hi = alen;
  while (lo < hi) { int mid = (lo + hi) >> 1; if (ids[mid] < s) lo = mid + 1; else hi = mid; }
  const int start = lo;
  hi = alen;
  while (lo < hi) { int mid = (lo + hi) >> 1; if (ids[mid] <= s) lo = mid + 1; else hi = mid; }
  const int end = lo;
  const int cnt = end - start;

  const int t = threadIdx.x;       // 0..127, cols 4t..4t+3
  float a0 = 0.f, a1 = 0.f, a2 = 0.f, a3 = 0.f;
  float b0 = 0.f, b1 = 0.f, b2 = 0.f, b3 = 0.f;
  const float* base = rep + (size_t)b * Av * Dv + t * 4;
  int a = start;
  for (; a + 2 <= end; a += 2) {
    float4 v = *(const float4*)(base + (size_t)a * Dv);
    float4 w = *(const float4*)(base + (size_t)(a + 1) * Dv);
    a0 += v.x; a1 += v.y; a2 += v.z; a3 += v.w;
    b0 += w.x; b1 += w.y; b2 += w.z; b3 += w.w;
  }
  if (a < end) {
    float4 v = *(const float4*)(base + (size_t)a * Dv);
    a0 += v.x; a1 += v.y; a2 += v.z; a3 += v.w;
  }
  a0 += b0; a1 += b1; a2 += b2; a3 += b3;
  const float inv = cnt > 0 ? 1.0f / (float)cnt : 0.0f;
  ushort4 o = { f2bf(a0 * inv), f2bf(a1 * inv), f2bf(a2 * inv), f2bf(a3 * inv) };
  *(ushort4*)(pooled + (size_t)bs * Dv + t * 4) = o;
  if (t == 0) counts[bs] = cnt;
}

// ---------------------------------------------------------------------------
// Kernel 2: W (fp32) -> bf16
// ---------------------------------------------------------------------------
__global__ __launch_bounds__(256)
void wconv_kernel(const float* __restrict__ W, u16* __restrict__ Wb) {
  const int i = (blockIdx.x * 256 + threadIdx.x) * 4;
  float4 v = *(const float4*)(W + i);
  ushort4 o = { f2bf(v.x), f2bf(v.y), f2bf(v.z), f2bf(v.w) };
  *(ushort4*)(Wb + i) = o;
}

// ---------------------------------------------------------------------------
// Kernel 3: per-batch sum of filled pooled rows + filled count (atomics into
// zeroed workspace). grid (B, 16) x 128 threads; thread t handles cols 4t..4t+3.
// ---------------------------------------------------------------------------
__global__ __launch_bounds__(128)
void avg_kernel(const u16* __restrict__ pooled, const int* __restrict__ counts,
                const int* __restrict__ seq_len, float* __restrict__ avg_sum,
                int* __restrict__ n_fill) {
  const int b = blockIdx.x;
  const int chunk = blockIdx.y;    // 0..15
  const int t = threadIdx.x;       // 0..127
  int slen = seq_len[b];
  slen = slen < 0 ? 0 : (slen > Sv ? Sv : slen);
  const int s0 = chunk * 128;
  float a0 = 0.f, a1 = 0.f, a2 = 0.f, a3 = 0.f;
  int filled = 0;
  for (int s = s0; s < s0 + 128; ++s) {
    if (s < slen && counts[b * Sv + s] > 0) {
      ++filled;
      ushort4 v = *(const ushort4*)(pooled + ((size_t)(b * Sv + s)) * Dv + t * 4);
      a0 += bf2f(v.x); a1 += bf2f(v.y); a2 += bf2f(v.z); a3 += bf2f(v.w);
    }
  }
  atomicAdd(&avg_sum[b * Dv + t * 4 + 0], a0);
  atomicAdd(&avg_sum[b * Dv + t * 4 + 1], a1);
  atomicAdd(&avg_sum[b * Dv + t * 4 + 2], a2);
  atomicAdd(&avg_sum[b * Dv + t * 4 + 3], a3);
  if (t == 0) atomicAdd(&n_fill[b], filled);
}

// ---------------------------------------------------------------------------
// Kernel 4: rows with cnt==0 (in-range) get the per-batch filled average;
// rows out of seq range get zeros. Nearly all blocks exit immediately.
// ---------------------------------------------------------------------------
__global__ __launch_bounds__(64)
void fixup_kernel(u16* __restrict__ pooled, const int* __restrict__ counts,
                  const int* __restrict__ seq_len, const float* __restrict__ avg_sum,
                  const int* __restrict__ n_fill) {
  const int bs = blockIdx.x;
  const int b = bs >> 11;
  const int s = bs & (Sv - 1);
  int slen = seq_len[b];
  slen = slen < 0 ? 0 : (slen > Sv ? Sv : slen);
  const int cnt = counts[bs];
  const int t = threadIdx.x;       // 0..63, cols 8t..8t+7
  if (s >= slen) {
    if (cnt != 0) {
      ushort4 z = {0, 0, 0, 0};
      *(ushort4*)(pooled + (size_t)bs * Dv + t * 8) = z;
      *(ushort4*)(pooled + (size_t)bs * Dv + t * 8 + 4) = z;
    }
    return;
  }
  if (cnt > 0) return;
  const int nf = n_fill[b];
  const float inv = 1.0f / (float)(nf > 0 ? nf : 1);
  float4 v0 = *(const float4*)(avg_sum + b * Dv + t * 8);
  float4 v1 = *(const float4*)(avg_sum + b * Dv + t * 8 + 4);
  ushort4 o0 = { f2bf(v0.x * inv), f2bf(v0.y * inv), f2bf(v0.z * inv), f2bf(v0.w * inv) };
  ushort4 o1 = { f2bf(v1.x * inv), f2bf(v1.y * inv), f2bf(v1.z * inv), f2bf(v1.w * inv) };
  *(ushort4*)(pooled + (size_t)bs * Dv + t * 8) = o0;
  *(ushort4*)(pooled + (size_t)bs * Dv + t * 8 + 4) = o1;
}

// ---------------------------------------------------------------------------
// Kernel 5: out[m,n] = sum_k pooled[m,k] * W[n,k] + bias[n]   (bf16 MFMA)
// m97-structure: 128x128 tile, BK=64, direct global_load_lds (16B) into
// LINEAR LDS (T2 swizzle is measured-null on 2-barrier structures), 2-barrier
// loop. Operand-SWAPPED mfma (b_frag first) so each lane's 4 acc regs are 4
// consecutive out columns -> float4 epilogue stores.
// ---------------------------------------------------------------------------
#define BM 128
#define BN 128
#define BK 64

__global__ __launch_bounds__(256, 2)
void gemm_kernel(const u16* __restrict__ A, const u16* __restrict__ Bw,
                 const float* __restrict__ bias, float* __restrict__ out) {
  __shared__ alignas(16) u16 As[BM * BK];   // 16 KB, linear [row][64]
  __shared__ alignas(16) u16 Bs[BN * BK];   // 16 KB
  const int tid = threadIdx.x;
  const int m0 = blockIdx.x * BM;
  const int n0 = blockIdx.y * BN;
  const int lane = tid & 63;
  const int wave = tid >> 6;
  const int wm = (wave & 1) * 64;
  const int wn = (wave >> 1) * 64;
  const int fr = lane & 15;        // fragment row/col within 16-tile
  const int fq = lane >> 4;        // quad -> k-subrange / out col group

  f32x4 acc[4][4];
#pragma unroll
  for (int i = 0; i < 4; ++i)
#pragma unroll
    for (int j = 0; j < 4; ++j) acc[i][j] = (f32x4){0.f, 0.f, 0.f, 0.f};

  const char* Ab = (const char*)A;
  const char* Bb = (const char*)Bw;

  for (int k0 = 0; k0 < Dv; k0 += BK) {
    __syncthreads();               // protect LDS from previous iter's readers
#pragma unroll
    for (int c = 0; c < 4; ++c) {
      const int off = (c * 256 + tid) * 16;     // byte offset within 16KB tile
      const int row = off >> 7;                 // 128 B per row (64 bf16)
      const int inb = off & 127;
      gl_lds16(Ab + (size_t)(m0 + row) * (Dv * 2) + k0 * 2 + inb, (char*)As + off);
      gl_lds16(Bb + (size_t)(n0 + row) * (Dv * 2) + k0 * 2 + inb, (char*)Bs + off);
    }
    __syncthreads();               // compiler emits vmcnt(0) drain: tiles resident

#pragma unroll
    for (int ks = 0; ks < 2; ++ks) {
      bf16x8 af[4], bfv[4];
#pragma unroll
      for (int mi = 0; mi < 4; ++mi)
        af[mi] = *(const bf16x8*)(As + (wm + mi * 16 + fr) * BK + ks * 32 + fq * 8);
#pragma unroll
      for (int ni = 0; ni < 4; ++ni)
        bfv[ni] = *(const bf16x8*)(Bs + (wn + ni * 16 + fr) * BK + ks * 32 + fq * 8);
#pragma unroll
      for (int mi = 0; mi < 4; ++mi)
#pragma unroll
        for (int ni = 0; ni < 4; ++ni)
          acc[mi][ni] = __builtin_amdgcn_mfma_f32_16x16x32_bf16(bfv[ni], af[mi], acc[mi][ni], 0, 0, 0);
    }
  }

  // swapped operands => D-row (fq*4+r) indexes n, D-col (fr) indexes m:
  // lane holds out[m0+wm+mi*16+fr][n0+wn+ni*16+fq*4 .. +3]  -> float4 store
#pragma unroll
  for (int mi = 0; mi < 4; ++mi) {
    const int row = m0 + wm + mi * 16 + fr;
#pragma unroll
    for (int ni = 0; ni < 4; ++ni) {
      const int colb = n0 + wn + ni * 16 + fq * 4;
      float4 bv = *(const float4*)(bias + colb);
      f32x4 v = acc[mi][ni];
      float4 o = { v[0] + bv.x, v[1] + bv.y, v[2] + bv.z, v[3] + bv.w };
      *(float4*)(out + (size_t)row * OUTv + colb) = o;
    }
  }
}

// ---------------------------------------------------------------------------
// Workspace layout (bytes):
//   [0,            16777216)  pooled bf16 [M, D]
//   [16777216,     17301504)  Wb bf16 [OUT, D]
//   [17301504,     17367040)  counts int [M]
//   [17367040,     17383424)  avg_sum float [B, D]
//   [17383424,     17383456)  n_fill int [B]
// ---------------------------------------------------------------------------
extern "C" void kernel_launch(void* const* d_in, const int* in_sizes, int n_in,
                              void* d_out, int out_size, void* d_ws, size_t ws_size,
                              hipStream_t stream) {
  (void)in_sizes; (void)n_in; (void)out_size; (void)ws_size;
  const float* rep     = (const float*)d_in[0];
  const int*   res_ids = (const int*)d_in[1];
  const int*   aa_len  = (const int*)d_in[2];
  const int*   seq_len = (const int*)d_in[3];
  const float* W       = (const float*)d_in[4];
  const float* bias    = (const float*)d_in[5];
  float* out = (float*)d_out;

  char* ws = (char*)d_ws;
  u16*   pooled  = (u16*)ws;
  u16*   Wb      = (u16*)(ws + 16777216);
  int*   counts  = (int*)(ws + 17301504);
  float* avg_sum = (float*)(ws + 17367040);
  int*   n_fill  = (int*)(ws + 17383424);

  hipMemsetAsync(avg_sum, 0, Bv * Dv * sizeof(float) + Bv * sizeof(int), stream);

  wconv_kernel<<<(OUTv * Dv) / (256 * 4), 256, 0, stream>>>(W, Wb);
  pool_kernel<<<Mv, 128, 0, stream>>>(rep, res_ids, aa_len, pooled, counts);
  avg_kernel<<<dim3(Bv, 16), 128, 0, stream>>>(pooled, counts, seq_len, avg_sum, n_fill);
  fixup_kernel<<<Mv, 64, 0, stream>>>(pooled, counts, seq_len, avg_sum, n_fill);
  gemm_kernel<<<dim3(Mv / BM, OUTv / BN), 256, 0, stream>>>(pooled, Wb, bias, out);
}

// Round 3
// 429.267 us; speedup vs baseline: 1.0405x; 1.0405x over previous
//
#include <hip/hip_runtime.h>
#include <cstdint>
#include <cstddef>

#define Bv 8
#define Av 16384
#define Sv 2048
#define Dv 512
#define OUTv 512
#define Mv (Bv * Sv)

using u16 = unsigned short;
using f32x4 = __attribute__((ext_vector_type(4))) float;
using bf16x8 = __attribute__((ext_vector_type(8))) short;

__device__ __forceinline__ u16 f2bf(float x) {
  union { float f; uint32_t u; } v; v.f = x;
  uint32_t u = v.u;
  uint32_t r = u + 0x7FFFu + ((u >> 16) & 1u);   // round-to-nearest-even
  return (u16)(r >> 16);
}
__device__ __forceinline__ float bf2f(u16 h) {
  union { uint32_t u; float f; } v; v.u = ((uint32_t)h) << 16; return v.f;
}

// async 16B global->LDS (m97 ladder step-3; compiler never auto-emits this)
__device__ __forceinline__ void gl_lds16(const void* g, void* s) {
  __builtin_amdgcn_global_load_lds(
      (const __attribute__((address_space(1))) unsigned int*)g,
      (__attribute__((address_space(3))) unsigned int*)s, 16, 0, 0);
}

// ---------------------------------------------------------------------------
// Kernel 0: segment-start scatter. starts[b][s] (s in [0,S]) = index of first
// valid atom with id >= s; starts[b][S] = alen. Replaces per-residue binary
// searches (28 dependent loads/block) with a single streaming pass.
// Total writes per batch = S+1, spread across threads.
// ---------------------------------------------------------------------------
__global__ __launch_bounds__(256)
void starts_kernel(const int* __restrict__ res_ids, const int* __restrict__ aa_len,
                   int* __restrict__ starts) {
  const int b = blockIdx.y;
  const int a = blockIdx.x * 256 + threadIdx.x;
  int alen = aa_len[b];
  alen = alen < 0 ? 0 : (alen > Av ? Av : alen);
  int* st = starts + b * (Sv + 1);
  if (a >= alen) {
    if (a == 0) {                        // alen == 0: whole table is 0
      for (int s = 0; s <= Sv; ++s) st[s] = 0;
    }
    return;
  }
  const int* ids = res_ids + b * Av;
  const int id = ids[a];
  const int p = (a == 0) ? -1 : ids[a - 1];
  for (int s = p + 1; s <= id; ++s) st[s] = a;
  if (a == alen - 1) {
    for (int s = id + 1; s <= Sv; ++s) st[s] = alen;
  }
}

// ---------------------------------------------------------------------------
// Kernel 1: segment-mean pooling. Block (b,s) reads its contiguous atom range
// [starts[s], starts[s+1]) — no searches, 2 range loads. 128 threads, 4 cols
// each, atom loop 4-deep (4 independent float4 loads in flight).
// ---------------------------------------------------------------------------
__global__ __launch_bounds__(128)
void pool_kernel(const float* __restrict__ rep, const int* __restrict__ starts,
                 u16* __restrict__ pooled) {
  const int bs = blockIdx.x;
  const int b = bs >> 11;          // /Sv
  const int s = bs & (Sv - 1);
  const int* st = starts + b * (Sv + 1);
  const int start = st[s];
  const int end = st[s + 1];
  const int cnt = end - start;

  const int t = threadIdx.x;       // 0..127, cols 4t..4t+3
  float p0 = 0.f, p1 = 0.f, p2 = 0.f, p3 = 0.f;
  float q0 = 0.f, q1 = 0.f, q2 = 0.f, q3 = 0.f;
  float r0 = 0.f, r1 = 0.f, r2 = 0.f, r3 = 0.f;
  float w0 = 0.f, w1 = 0.f, w2 = 0.f, w3 = 0.f;
  const float* base = rep + (size_t)b * Av * Dv + t * 4;
  int a = start;
  for (; a + 4 <= end; a += 4) {
    float4 v0 = *(const float4*)(base + (size_t)(a + 0) * Dv);
    float4 v1 = *(const float4*)(base + (size_t)(a + 1) * Dv);
    float4 v2 = *(const float4*)(base + (size_t)(a + 2) * Dv);
    float4 v3 = *(const float4*)(base + (size_t)(a + 3) * Dv);
    p0 += v0.x; p1 += v0.y; p2 += v0.z; p3 += v0.w;
    q0 += v1.x; q1 += v1.y; q2 += v1.z; q3 += v1.w;
    r0 += v2.x; r1 += v2.y; r2 += v2.z; r3 += v2.w;
    w0 += v3.x; w1 += v3.y; w2 += v3.z; w3 += v3.w;
  }
  for (; a < end; ++a) {
    float4 v = *(const float4*)(base + (size_t)a * Dv);
    p0 += v.x; p1 += v.y; p2 += v.z; p3 += v.w;
  }
  p0 += q0 + r0 + w0; p1 += q1 + r1 + w1; p2 += q2 + r2 + w2; p3 += q3 + r3 + w3;
  const float inv = cnt > 0 ? 1.0f / (float)cnt : 0.0f;
  ushort4 o = { f2bf(p0 * inv), f2bf(p1 * inv), f2bf(p2 * inv), f2bf(p3 * inv) };
  *(ushort4*)(pooled + (size_t)bs * Dv + t * 4) = o;
}

// ---------------------------------------------------------------------------
// Kernel 2: W (fp32) -> bf16
// ---------------------------------------------------------------------------
__global__ __launch_bounds__(256)
void wconv_kernel(const float* __restrict__ W, u16* __restrict__ Wb) {
  const int i = (blockIdx.x * 256 + threadIdx.x) * 4;
  float4 v = *(const float4*)(W + i);
  ushort4 o = { f2bf(v.x), f2bf(v.y), f2bf(v.z), f2bf(v.w) };
  *(ushort4*)(Wb + i) = o;
}

// ---------------------------------------------------------------------------
// Kernel 3: per-batch sum of filled pooled rows + filled count (atomics into
// zeroed workspace). grid (B, 128) x 128 threads; block handles 16 s-rows,
// thread t handles cols 4t..4t+3. 1024 blocks -> full chip, short loops.
// ---------------------------------------------------------------------------
__global__ __launch_bounds__(128)
void avg_kernel(const u16* __restrict__ pooled, const int* __restrict__ starts,
                const int* __restrict__ seq_len, float* __restrict__ avg_sum,
                int* __restrict__ n_fill) {
  const int b = blockIdx.x;
  const int chunk = blockIdx.y;    // 0..127
  const int t = threadIdx.x;       // 0..127
  int slen = seq_len[b];
  slen = slen < 0 ? 0 : (slen > Sv ? Sv : slen);
  const int* st = starts + b * (Sv + 1);
  const int s0 = chunk * 16;
  float a0 = 0.f, a1 = 0.f, a2 = 0.f, a3 = 0.f;
  int filled = 0;
  for (int s = s0; s < s0 + 16; ++s) {
    if (s < slen && st[s + 1] - st[s] > 0) {
      ++filled;
      ushort4 v = *(const ushort4*)(pooled + ((size_t)(b * Sv + s)) * Dv + t * 4);
      a0 += bf2f(v.x); a1 += bf2f(v.y); a2 += bf2f(v.z); a3 += bf2f(v.w);
    }
  }
  atomicAdd(&avg_sum[b * Dv + t * 4 + 0], a0);
  atomicAdd(&avg_sum[b * Dv + t * 4 + 1], a1);
  atomicAdd(&avg_sum[b * Dv + t * 4 + 2], a2);
  atomicAdd(&avg_sum[b * Dv + t * 4 + 3], a3);
  if (t == 0 && filled > 0) atomicAdd(&n_fill[b], filled);
}

// ---------------------------------------------------------------------------
// Kernel 4: rows with cnt==0 (in-range) get the per-batch filled average;
// rows out of seq range get zeros. Nearly all blocks exit immediately.
// ---------------------------------------------------------------------------
__global__ __launch_bounds__(64)
void fixup_kernel(u16* __restrict__ pooled, const int* __restrict__ starts,
                  const int* __restrict__ seq_len, const float* __restrict__ avg_sum,
                  const int* __restrict__ n_fill) {
  const int bs = blockIdx.x;
  const int b = bs >> 11;
  const int s = bs & (Sv - 1);
  int slen = seq_len[b];
  slen = slen < 0 ? 0 : (slen > Sv ? Sv : slen);
  const int* st = starts + b * (Sv + 1);
  const int cnt = st[s + 1] - st[s];
  const int t = threadIdx.x;       // 0..63, cols 8t..8t+7
  if (s >= slen) {
    if (cnt != 0) {
      ushort4 z = {0, 0, 0, 0};
      *(ushort4*)(pooled + (size_t)bs * Dv + t * 8) = z;
      *(ushort4*)(pooled + (size_t)bs * Dv + t * 8 + 4) = z;
    }
    return;
  }
  if (cnt > 0) return;
  const int nf = n_fill[b];
  const float inv = 1.0f / (float)(nf > 0 ? nf : 1);
  float4 v0 = *(const float4*)(avg_sum + b * Dv + t * 8);
  float4 v1 = *(const float4*)(avg_sum + b * Dv + t * 8 + 4);
  ushort4 o0 = { f2bf(v0.x * inv), f2bf(v0.y * inv), f2bf(v0.z * inv), f2bf(v0.w * inv) };
  ushort4 o1 = { f2bf(v1.x * inv), f2bf(v1.y * inv), f2bf(v1.z * inv), f2bf(v1.w * inv) };
  *(ushort4*)(pooled + (size_t)bs * Dv + t * 8) = o0;
  *(ushort4*)(pooled + (size_t)bs * Dv + t * 8 + 4) = o1;
}

// ---------------------------------------------------------------------------
// Kernel 5: out[m,n] = sum_k pooled[m,k] * W[n,k] + bias[n]   (bf16 MFMA)
// m97-structure: 128x128 tile, BK=64, direct global_load_lds (16B) into
// LINEAR LDS (T2 swizzle measured-null on 2-barrier structures), 2-barrier
// loop. Operand-SWAPPED mfma (b_frag first) so each lane's 4 acc regs are 4
// consecutive out columns -> float4 epilogue stores.  [verified round 2]
// ---------------------------------------------------------------------------
#define BM 128
#define BN 128
#define BK 64

__global__ __launch_bounds__(256, 2)
void gemm_kernel(const u16* __restrict__ A, const u16* __restrict__ Bw,
                 const float* __restrict__ bias, float* __restrict__ out) {
  __shared__ alignas(16) u16 As[BM * BK];   // 16 KB, linear [row][64]
  __shared__ alignas(16) u16 Bs[BN * BK];   // 16 KB
  const int tid = threadIdx.x;
  const int m0 = blockIdx.x * BM;
  const int n0 = blockIdx.y * BN;
  const int lane = tid & 63;
  const int wave = tid >> 6;
  const int wm = (wave & 1) * 64;
  const int wn = (wave >> 1) * 64;
  const int fr = lane & 15;        // fragment row/col within 16-tile
  const int fq = lane >> 4;        // quad -> k-subrange / out col group

  f32x4 acc[4][4];
#pragma unroll
  for (int i = 0; i < 4; ++i)
#pragma unroll
    for (int j = 0; j < 4; ++j) acc[i][j] = (f32x4){0.f, 0.f, 0.f, 0.f};

  const char* Ab = (const char*)A;
  const char* Bb = (const char*)Bw;

  for (int k0 = 0; k0 < Dv; k0 += BK) {
    __syncthreads();               // protect LDS from previous iter's readers
#pragma unroll
    for (int c = 0; c < 4; ++c) {
      const int off = (c * 256 + tid) * 16;     // byte offset within 16KB tile
      const int row = off >> 7;                 // 128 B per row (64 bf16)
      const int inb = off & 127;
      gl_lds16(Ab + (size_t)(m0 + row) * (Dv * 2) + k0 * 2 + inb, (char*)As + off);
      gl_lds16(Bb + (size_t)(n0 + row) * (Dv * 2) + k0 * 2 + inb, (char*)Bs + off);
    }
    __syncthreads();               // compiler emits vmcnt(0) drain: tiles resident

#pragma unroll
    for (int ks = 0; ks < 2; ++ks) {
      bf16x8 af[4], bfv[4];
#pragma unroll
      for (int mi = 0; mi < 4; ++mi)
        af[mi] = *(const bf16x8*)(As + (wm + mi * 16 + fr) * BK + ks * 32 + fq * 8);
#pragma unroll
      for (int ni = 0; ni < 4; ++ni)
        bfv[ni] = *(const bf16x8*)(Bs + (wn + ni * 16 + fr) * BK + ks * 32 + fq * 8);
#pragma unroll
      for (int mi = 0; mi < 4; ++mi)
#pragma unroll
        for (int ni = 0; ni < 4; ++ni)
          acc[mi][ni] = __builtin_amdgcn_mfma_f32_16x16x32_bf16(bfv[ni], af[mi], acc[mi][ni], 0, 0, 0);
    }
  }

  // swapped operands => D-row (fq*4+r) indexes n, D-col (fr) indexes m:
  // lane holds out[m0+wm+mi*16+fr][n0+wn+ni*16+fq*4 .. +3]  -> float4 store
#pragma unroll
  for (int mi = 0; mi < 4; ++mi) {
    const int row = m0 + wm + mi * 16 + fr;
#pragma unroll
    for (int ni = 0; ni < 4; ++ni) {
      const int colb = n0 + wn + ni * 16 + fq * 4;
      float4 bv = *(const float4*)(bias + colb);
      f32x4 v = acc[mi][ni];
      float4 o = { v[0] + bv.x, v[1] + bv.y, v[2] + bv.z, v[3] + bv.w };
      *(float4*)(out + (size_t)row * OUTv + colb) = o;
    }
  }
}

// ---------------------------------------------------------------------------
// Workspace layout (bytes):
//   [0,            16777216)  pooled bf16 [M, D]
//   [16777216,     17301504)  Wb bf16 [OUT, D]
//   [17301504,     17367072)  starts int [B, S+1]
//   [17367072,     17383456)  avg_sum float [B, D]
//   [17383456,     17383488)  n_fill int [B]
// ---------------------------------------------------------------------------
extern "C" void kernel_launch(void* const* d_in, const int* in_sizes, int n_in,
                              void* d_out, int out_size, void* d_ws, size_t ws_size,
                              hipStream_t stream) {
  (void)in_sizes; (void)n_in; (void)out_size; (void)ws_size;
  const float* rep     = (const float*)d_in[0];
  const int*   res_ids = (const int*)d_in[1];
  const int*   aa_len  = (const int*)d_in[2];
  const int*   seq_len = (const int*)d_in[3];
  const float* W       = (const float*)d_in[4];
  const float* bias    = (const float*)d_in[5];
  float* out = (float*)d_out;

  char* ws = (char*)d_ws;
  u16*   pooled  = (u16*)ws;
  u16*   Wb      = (u16*)(ws + 16777216);
  int*   starts  = (int*)(ws + 17301504);
  float* avg_sum = (float*)(ws + 17367072);
  int*   n_fill  = (int*)(ws + 17383456);

  hipMemsetAsync(avg_sum, 0, Bv * Dv * sizeof(float) + Bv * sizeof(int), stream);

  wconv_kernel<<<(OUTv * Dv) / (256 * 4), 256, 0, stream>>>(W, Wb);
  starts_kernel<<<dim3(Av / 256, Bv), 256, 0, stream>>>(res_ids, aa_len, starts);
  pool_kernel<<<Mv, 128, 0, stream>>>(rep, starts, pooled);
  avg_kernel<<<dim3(Bv, 128), 128, 0, stream>>>(pooled, starts, seq_len, avg_sum, n_fill);
  fixup_kernel<<<Mv, 64, 0, stream>>>(pooled, starts, seq_len, avg_sum, n_fill);
  gemm_kernel<<<dim3(Mv / BM, OUTv / BN), 256, 0, stream>>>(pooled, Wb, bias, out);
}

// Round 4
// 424.980 us; speedup vs baseline: 1.0510x; 1.0101x over previous
//
#include <hip/hip_runtime.h>
#include <cstdint>
#include <cstddef>

#define Bv 8
#define Av 16384
#define Sv 2048
#define Dv 512
#define OUTv 512
#define Mv (Bv * Sv)

using u16 = unsigned short;
using f32x4 = __attribute__((ext_vector_type(4))) float;
using bf16x8 = __attribute__((ext_vector_type(8))) short;

__device__ __forceinline__ u16 f2bf(float x) {
  union { float f; uint32_t u; } v; v.f = x;
  uint32_t u = v.u;
  uint32_t r = u + 0x7FFFu + ((u >> 16) & 1u);   // round-to-nearest-even
  return (u16)(r >> 16);
}
__device__ __forceinline__ float bf2f(u16 h) {
  union { uint32_t u; float f; } v; v.u = ((uint32_t)h) << 16; return v.f;
}

// async 16B global->LDS (m97 ladder step-3; compiler never auto-emits this)
__device__ __forceinline__ void gl_lds16(const void* g, void* s) {
  __builtin_amdgcn_global_load_lds(
      (const __attribute__((address_space(1))) unsigned int*)g,
      (__attribute__((address_space(3))) unsigned int*)s, 16, 0, 0);
}

// ---------------------------------------------------------------------------
// Kernel 0: segment-start scatter. starts[b][s] (s in [0,S]) = index of first
// valid atom with id >= s; starts[b][S] = alen. One streaming pass.
// ---------------------------------------------------------------------------
__global__ __launch_bounds__(256)
void starts_kernel(const int* __restrict__ res_ids, const int* __restrict__ aa_len,
                   int* __restrict__ starts) {
  const int b = blockIdx.y;
  const int a = blockIdx.x * 256 + threadIdx.x;
  int alen = aa_len[b];
  alen = alen < 0 ? 0 : (alen > Av ? Av : alen);
  int* st = starts + b * (Sv + 1);
  if (a >= alen) {
    if (a == 0) {                        // alen == 0: whole table is 0
      for (int s = 0; s <= Sv; ++s) st[s] = 0;
    }
    return;
  }
  const int* ids = res_ids + b * Av;
  const int id = ids[a];
  const int p = (a == 0) ? -1 : ids[a - 1];
  for (int s = p + 1; s <= id; ++s) st[s] = a;
  if (a == alen - 1) {
    for (int s = id + 1; s <= Sv; ++s) st[s] = alen;
  }
}

// ---------------------------------------------------------------------------
// Kernel 1: segment-mean pooling. Block (b,s) reads its contiguous atom range
// [starts[s], starts[s+1]). 128 threads, 4 cols each, 4 loads in flight.
// ---------------------------------------------------------------------------
__global__ __launch_bounds__(128)
void pool_kernel(const float* __restrict__ rep, const int* __restrict__ starts,
                 u16* __restrict__ pooled) {
  const int bs = blockIdx.x;
  const int b = bs >> 11;          // /Sv
  const int s = bs & (Sv - 1);
  const int* st = starts + b * (Sv + 1);
  const int start = st[s];
  const int end = st[s + 1];
  const int cnt = end - start;

  const int t = threadIdx.x;       // 0..127, cols 4t..4t+3
  float p0 = 0.f, p1 = 0.f, p2 = 0.f, p3 = 0.f;
  float q0 = 0.f, q1 = 0.f, q2 = 0.f, q3 = 0.f;
  float r0 = 0.f, r1 = 0.f, r2 = 0.f, r3 = 0.f;
  float w0 = 0.f, w1 = 0.f, w2 = 0.f, w3 = 0.f;
  const float* base = rep + (size_t)b * Av * Dv + t * 4;
  int a = start;
  for (; a + 4 <= end; a += 4) {
    float4 v0 = *(const float4*)(base + (size_t)(a + 0) * Dv);
    float4 v1 = *(const float4*)(base + (size_t)(a + 1) * Dv);
    float4 v2 = *(const float4*)(base + (size_t)(a + 2) * Dv);
    float4 v3 = *(const float4*)(base + (size_t)(a + 3) * Dv);
    p0 += v0.x; p1 += v0.y; p2 += v0.z; p3 += v0.w;
    q0 += v1.x; q1 += v1.y; q2 += v1.z; q3 += v1.w;
    r0 += v2.x; r1 += v2.y; r2 += v2.z; r3 += v2.w;
    w0 += v3.x; w1 += v3.y; w2 += v3.z; w3 += v3.w;
  }
  for (; a < end; ++a) {
    float4 v = *(const float4*)(base + (size_t)a * Dv);
    p0 += v.x; p1 += v.y; p2 += v.z; p3 += v.w;
  }
  p0 += q0 + r0 + w0; p1 += q1 + r1 + w1; p2 += q2 + r2 + w2; p3 += q3 + r3 + w3;
  const float inv = cnt > 0 ? 1.0f / (float)cnt : 0.0f;
  ushort4 o = { f2bf(p0 * inv), f2bf(p1 * inv), f2bf(p2 * inv), f2bf(p3 * inv) };
  *(ushort4*)(pooled + (size_t)bs * Dv + t * 4) = o;
}

// ---------------------------------------------------------------------------
// Kernel 2: W (fp32) -> bf16. Block 0 additionally zeroes avg_sum/n_fill
// (this kernel is first in the stream, so ordering is guaranteed).
// ---------------------------------------------------------------------------
__global__ __launch_bounds__(256)
void wconv_kernel(const float* __restrict__ W, u16* __restrict__ Wb,
                  float* __restrict__ avg_sum, int* __restrict__ n_fill) {
  const int i = (blockIdx.x * 256 + threadIdx.x) * 4;
  float4 v = *(const float4*)(W + i);
  ushort4 o = { f2bf(v.x), f2bf(v.y), f2bf(v.z), f2bf(v.w) };
  *(ushort4*)(Wb + i) = o;
  if (blockIdx.x == 0) {
    const int t = threadIdx.x;
    float4 z4 = {0.f, 0.f, 0.f, 0.f};
#pragma unroll
    for (int j = 0; j < (Bv * Dv) / (4 * 256); ++j)
      *(float4*)(avg_sum + (j * 256 + t) * 4) = z4;
    if (t < Bv) n_fill[t] = 0;
  }
}

// ---------------------------------------------------------------------------
// Kernel 3: per-batch sum of filled pooled rows + filled count (atomics into
// zeroed workspace). grid (B, 128) x 128 threads; block handles 16 s-rows.
// ---------------------------------------------------------------------------
__global__ __launch_bounds__(128)
void avg_kernel(const u16* __restrict__ pooled, const int* __restrict__ starts,
                const int* __restrict__ seq_len, float* __restrict__ avg_sum,
                int* __restrict__ n_fill) {
  const int b = blockIdx.x;
  const int chunk = blockIdx.y;    // 0..127
  const int t = threadIdx.x;       // 0..127
  int slen = seq_len[b];
  slen = slen < 0 ? 0 : (slen > Sv ? Sv : slen);
  const int* st = starts + b * (Sv + 1);
  const int s0 = chunk * 16;
  float a0 = 0.f, a1 = 0.f, a2 = 0.f, a3 = 0.f;
  int filled = 0;
  for (int s = s0; s < s0 + 16; ++s) {
    if (s < slen && st[s + 1] - st[s] > 0) {
      ++filled;
      ushort4 v = *(const ushort4*)(pooled + ((size_t)(b * Sv + s)) * Dv + t * 4);
      a0 += bf2f(v.x); a1 += bf2f(v.y); a2 += bf2f(v.z); a3 += bf2f(v.w);
    }
  }
  if (filled > 0) {
    atomicAdd(&avg_sum[b * Dv + t * 4 + 0], a0);
    atomicAdd(&avg_sum[b * Dv + t * 4 + 1], a1);
    atomicAdd(&avg_sum[b * Dv + t * 4 + 2], a2);
    atomicAdd(&avg_sum[b * Dv + t * 4 + 3], a3);
    if (t == 0) atomicAdd(&n_fill[b], filled);
  }
}

// ---------------------------------------------------------------------------
// Kernel 4: finalize avg -> bf16 row per batch; block 0 also writes zero row.
// Replaces the old 16384-block fixup_kernel (its semantics moved into gemm's
// per-row source redirection).
// ---------------------------------------------------------------------------
__global__ __launch_bounds__(128)
void avgvec_kernel(const float* __restrict__ avg_sum, const int* __restrict__ n_fill,
                   u16* __restrict__ avgbf, u16* __restrict__ zrow) {
  const int b = blockIdx.x;        // 0..Bv-1
  const int t = threadIdx.x;       // 0..127
  const int nf = n_fill[b];
  const float inv = 1.0f / (float)(nf > 0 ? nf : 1);
  float4 v = *(const float4*)(avg_sum + b * Dv + t * 4);
  ushort4 o = { f2bf(v.x * inv), f2bf(v.y * inv), f2bf(v.z * inv), f2bf(v.w * inv) };
  *(ushort4*)(avgbf + (size_t)b * Dv + t * 4) = o;
  if (b == 0) {
    ushort4 z = {0, 0, 0, 0};
    *(ushort4*)(zrow + t * 4) = z;
  }
}

// ---------------------------------------------------------------------------
// Kernel 5: out[m,n] = sum_k Arow[m,k] * W[n,k] + bias[n]   (bf16 MFMA)
// m97-structure: 128x128 tile, BK=64, global_load_lds (16B) into linear LDS.
// Per-row A-source redirection (fixup fused): filled row -> pooled row;
// unfilled in-range -> per-batch avg row; out-of-range -> zero row (out=bias).
// global_load_lds source is per-lane, dest stays linear (rule #21 respected).
// Operand-swapped mfma -> float4 epilogue stores.  [core verified round 2/3]
// ---------------------------------------------------------------------------
#define BM 128
#define BN 128
#define BK 64

__global__ __launch_bounds__(256, 2)
void gemm_kernel(const u16* __restrict__ A, const u16* __restrict__ Bw,
                 const int* __restrict__ starts, const int* __restrict__ seq_len,
                 const u16* __restrict__ avgbf, const u16* __restrict__ zrow,
                 const float* __restrict__ bias, float* __restrict__ out) {
  __shared__ alignas(16) u16 As[BM * BK];   // 16 KB, linear [row][64]
  __shared__ alignas(16) u16 Bs[BN * BK];   // 16 KB
  const int tid = threadIdx.x;
  const int m0 = blockIdx.x * BM;
  const int n0 = blockIdx.y * BN;
  const int b = m0 >> 11;                   // BM=128 divides Sv -> one batch/block
  int slen = seq_len[b];
  slen = slen < 0 ? 0 : (slen > Sv ? Sv : slen);
  const int* st = starts + b * (Sv + 1);

  // per-thread staging geometry: chunk c covers row c*32 + tid/8, bytes (tid&7)*16
  const int inb = (tid & 7) * 16;
  const char* aSrc[4];
  const char* bSrc[4];
#pragma unroll
  for (int c = 0; c < 4; ++c) {
    const int r = c * 32 + (tid >> 3);      // 0..127
    const int rm = m0 + r;
    const int s = rm & (Sv - 1);
    const int cnt = st[s + 1] - st[s];
    const u16* src;
    if (s >= slen)      src = zrow;
    else if (cnt > 0)   src = A + (size_t)rm * Dv;
    else                src = avgbf + (size_t)b * Dv;
    aSrc[c] = (const char*)src + inb;
    bSrc[c] = (const char*)(Bw + (size_t)(n0 + r) * Dv) + inb;
  }

  const int lane = tid & 63;
  const int wave = tid >> 6;
  const int wm = (wave & 1) * 64;
  const int wn = (wave >> 1) * 64;
  const int fr = lane & 15;        // fragment row/col within 16-tile
  const int fq = lane >> 4;        // quad -> k-subrange / out col group

  f32x4 acc[4][4];
#pragma unroll
  for (int i = 0; i < 4; ++i)
#pragma unroll
    for (int j = 0; j < 4; ++j) acc[i][j] = (f32x4){0.f, 0.f, 0.f, 0.f};

  for (int k0 = 0; k0 < Dv; k0 += BK) {
    __syncthreads();               // protect LDS from previous iter's readers
#pragma unroll
    for (int c = 0; c < 4; ++c) {
      const int off = (c * 256 + tid) * 16;     // byte offset within 16KB tile
      gl_lds16(aSrc[c] + k0 * 2, (char*)As + off);
      gl_lds16(bSrc[c] + k0 * 2, (char*)Bs + off);
    }
    __syncthreads();               // compiler emits vmcnt(0) drain: tiles resident

#pragma unroll
    for (int ks = 0; ks < 2; ++ks) {
      bf16x8 af[4], bfv[4];
#pragma unroll
      for (int mi = 0; mi < 4; ++mi)
        af[mi] = *(const bf16x8*)(As + (wm + mi * 16 + fr) * BK + ks * 32 + fq * 8);
#pragma unroll
      for (int ni = 0; ni < 4; ++ni)
        bfv[ni] = *(const bf16x8*)(Bs + (wn + ni * 16 + fr) * BK + ks * 32 + fq * 8);
#pragma unroll
      for (int mi = 0; mi < 4; ++mi)
#pragma unroll
        for (int ni = 0; ni < 4; ++ni)
          acc[mi][ni] = __builtin_amdgcn_mfma_f32_16x16x32_bf16(bfv[ni], af[mi], acc[mi][ni], 0, 0, 0);
    }
  }

  // swapped operands => D-row (fq*4+r) indexes n, D-col (fr) indexes m:
  // lane holds out[m0+wm+mi*16+fr][n0+wn+ni*16+fq*4 .. +3]  -> float4 store
#pragma unroll
  for (int mi = 0; mi < 4; ++mi) {
    const int row = m0 + wm + mi * 16 + fr;
#pragma unroll
    for (int ni = 0; ni < 4; ++ni) {
      const int colb = n0 + wn + ni * 16 + fq * 4;
      float4 bv = *(const float4*)(bias + colb);
      f32x4 v = acc[mi][ni];
      float4 o = { v[0] + bv.x, v[1] + bv.y, v[2] + bv.z, v[3] + bv.w };
      *(float4*)(out + (size_t)row * OUTv + colb) = o;
    }
  }
}

// ---------------------------------------------------------------------------
// Workspace layout (bytes):
//   [0,            16777216)  pooled bf16 [M, D]
//   [16777216,     17301504)  Wb bf16 [OUT, D]
//   [17301504,     17367072)  starts int [B, S+1]
//   [17367072,     17383456)  avg_sum float [B, D]
//   [17383456,     17383488)  n_fill int [B]
//   [17383488,     17391680)  avgbf bf16 [B, D]
//   [17391680,     17392704)  zrow bf16 [D]
// ---------------------------------------------------------------------------
extern "C" void kernel_launch(void* const* d_in, const int* in_sizes, int n_in,
                              void* d_out, int out_size, void* d_ws, size_t ws_size,
                              hipStream_t stream) {
  (void)in_sizes; (void)n_in; (void)out_size; (void)ws_size;
  const float* rep     = (const float*)d_in[0];
  const int*   res_ids = (const int*)d_in[1];
  const int*   aa_len  = (const int*)d_in[2];
  const int*   seq_len = (const int*)d_in[3];
  const float* W       = (const float*)d_in[4];
  const float* bias    = (const float*)d_in[5];
  float* out = (float*)d_out;

  char* ws = (char*)d_ws;
  u16*   pooled  = (u16*)ws;
  u16*   Wb      = (u16*)(ws + 16777216);
  int*   starts  = (int*)(ws + 17301504);
  float* avg_sum = (float*)(ws + 17367072);
  int*   n_fill  = (int*)(ws + 17383456);
  u16*   avgbf   = (u16*)(ws + 17383488);
  u16*   zrow    = (u16*)(ws + 17391680);

  wconv_kernel<<<(OUTv * Dv) / (256 * 4), 256, 0, stream>>>(W, Wb, avg_sum, n_fill);
  starts_kernel<<<dim3(Av / 256, Bv), 256, 0, stream>>>(res_ids, aa_len, starts);
  pool_kernel<<<Mv, 128, 0, stream>>>(rep, starts, pooled);
  avg_kernel<<<dim3(Bv, 128), 128, 0, stream>>>(pooled, starts, seq_len, avg_sum, n_fill);
  avgvec_kernel<<<Bv, 128, 0, stream>>>(avg_sum, n_fill, avgbf, zrow);
  gemm_kernel<<<dim3(Mv / BM, OUTv / BN), 256, 0, stream>>>(
      pooled, Wb, starts, seq_len, avgbf, zrow, bias, out);
}